// Round 2
// baseline (1161.654 us; speedup 1.0000x reference)
//
#include <hip/hip_runtime.h>

#define HOUT 15
#define WOUT 15
// input  (32, 32, 32, 32, 16)  fp32
// ncv    (32, 32, 15, 15, 16)  fp32
// w      (3, 3, 32, 4, 4, 32)  fp32
// out    (32, 32, 15, 15, 16)  fp32

typedef float v2 __attribute__((ext_vector_type(2)));

// DPP butterfly add step (ctrl must be a literal)
#define DPP_ADDF(x, ctrl) \
    ((x) + __builtin_bit_cast(float, __builtin_amdgcn_update_dpp( \
        0, __builtin_bit_cast(int, (x)), (ctrl), 0xF, 0xF, true)))

// ---------------- pass 0: transpose w (d <-> m) -----------------------------
// w[kl][n][x][d][m]  ->  w2[n][kl][x][m][d]   (147456 floats = 576 KB)
// so each lane m reads {w[x,0..3,m]} as one float4, coalesced across lanes.
__global__ __launch_bounds__(256) void prep_w(const float* __restrict__ wt,
                                              float* __restrict__ w2)
{
    const int t  = blockIdx.x * 256 + threadIdx.x;   // dest index, 0..147455
    const int d  = t & 3;
    const int m  = (t >> 2) & 31;
    const int x  = (t >> 7) & 3;
    const int r  = t >> 9;        // n*9 + kl
    const int kl = r % 9;
    const int n  = r / 9;
    w2[t] = wt[((((kl * 32 + n) * 4 + x) * 4 + d) * 32) + m];
}

// ---------------- pass 1: attention + accumulate over half the n range -----
// One 32-lane group per output position (b,h,w); lane = m. 4 groups / block.
// blockIdx.y = n-split (0: n=0..15 -> part0=out, 1: n=16..31 -> part1=ws).
// No LDS, no barriers; w read via L1/L2 (18 KB per-n slice, cache-resident).
// Grid 3600 blocks x 2 waves = 28 waves/CU -> 7 waves/SIMD for latency hiding.
__global__ __launch_bounds__(128, 7) void caps_part(
    const float* __restrict__ input,
    const float* __restrict__ ncv,
    const float* __restrict__ w2,
    float* __restrict__ part0,
    float* __restrict__ part1)
{
    const int tid  = threadIdx.x;
    const int grp  = tid >> 5;      // 0..3
    const int lane = tid & 31;      // m

    const int pos = blockIdx.x * 4 + grp;      // 0..7199
    const int b   = pos / (HOUT * WOUT);
    const int hw  = pos % (HOUT * WOUT);
    const int h   = hw / WOUT;
    const int wo  = hw % WOUT;
    const int h0  = h * 2, w0 = wo * 2;

    const int n0 = blockIdx.y * 16;

    // ncv[b, m=lane, h, wo, 0..15] as 8 x float2
    const float* ncv_p = ncv + ((((size_t)b * 32 + lane) * HOUT + h) * WOUT + wo) * 16;
    v2 cv2[8];
#pragma unroll
    for (int j = 0; j < 8; ++j) cv2[j] = *(const v2*)(ncv_p + j * 2);

    v2 acc2[8];
#pragma unroll
    for (int j = 0; j < 8; ++j) acc2[j] = (v2){0.0f, 0.0f};

    const float* ip0 = input + ((((size_t)b * 32 + n0) * 32 + h0) * 32 + w0) * 16;
    const float* wp0 = w2 + (size_t)n0 * 4608 + lane * 4;

    for (int ni = 0; ni < 16; ++ni) {
        const float* ipn = ip0 + (size_t)ni * 16384;       // 32*32*16
        const float* wpn = wp0 + (size_t)ni * 4608;        // 9*4*128

#pragma unroll
        for (int kl = 0; kl < 9; ++kl) {
            const int k = kl / 3, l = kl % 3;
            const float* ip = ipn + (k * 32 + l) * 16;

            float av[16];
#pragma unroll
            for (int j = 0; j < 16; j += 4) {
                float4 t4 = *(const float4*)(ip + j);
                av[j] = t4.x; av[j + 1] = t4.y; av[j + 2] = t4.z; av[j + 3] = t4.w;
            }

            // w[x][0..3][m] for this (n,kl): 4 coalesced float4 loads
            const float* wp = wpn + kl * 512;
            float4 wx[4];
#pragma unroll
            for (int x = 0; x < 4; ++x) wx[x] = *(const float4*)(wp + x * 128);

            // u[a,d] = sum_x av[a,x] * w[x,d,m]; packed d-pairs
            v2 u2[8];
#pragma unroll
            for (int x = 0; x < 4; ++x) {
                v2 wlo = {wx[x].x, wx[x].y};
                v2 whi = {wx[x].z, wx[x].w};
#pragma unroll
                for (int a = 0; a < 4; ++a) {
                    v2 sp = {av[a * 4 + x], av[a * 4 + x]};
                    if (x == 0) {
                        u2[a * 2]     = sp * wlo;       // pk_mul: no zero-init
                        u2[a * 2 + 1] = sp * whi;
                    } else {
                        u2[a * 2]     = __builtin_elementwise_fma(sp, wlo, u2[a * 2]);
                        u2[a * 2 + 1] = __builtin_elementwise_fma(sp, whi, u2[a * 2 + 1]);
                    }
                }
            }

            // logit = 0.25 * <u, cv>;  e = exp(logit) = exp2(dot * 0.25*log2e)
            v2 d0 = {0.f, 0.f}, d1 = {0.f, 0.f};
#pragma unroll
            for (int j = 0; j < 4; ++j) {
                d0 = __builtin_elementwise_fma(u2[j],     cv2[j],     d0);
                d1 = __builtin_elementwise_fma(u2[j + 4], cv2[j + 4], d1);
            }
            v2 dd = d0 + d1;
            float e = __builtin_exp2f((dd.x + dd.y) * 0.36067376022224085f);

            // sum over 32 lanes (m): 4 DPP adds + 1 swizzle (xor16)
            // post-xor2 quads are uniform, so half_mirror==xor4, mirror==xor8
            float s = e;
            s = DPP_ADDF(s, 0xB1);    // quad_perm [1,0,3,2]  == xor1
            s = DPP_ADDF(s, 0x4E);    // quad_perm [2,3,0,1]  == xor2
            s = DPP_ADDF(s, 0x141);   // row_half_mirror      == xor4 here
            s = DPP_ADDF(s, 0x140);   // row_mirror           == xor8 here
            s += __builtin_bit_cast(float,
                  __builtin_amdgcn_ds_swizzle(__builtin_bit_cast(int, s), 0x401F)); // xor16

            float p = e * __builtin_amdgcn_rcpf(s);
            v2 p2 = {p, p};
#pragma unroll
            for (int j = 0; j < 8; ++j)
                acc2[j] = __builtin_elementwise_fma(p2, u2[j], acc2[j]);
        }
    }

    // store partial in out-layout: [b][m][h][w][16]
    float* op = (blockIdx.y == 0 ? part0 : part1)
              + ((((size_t)b * 32 + lane) * HOUT + h) * WOUT + wo) * 16;
#pragma unroll
    for (int j = 0; j < 4; ++j) {
        float4 r;
        r.x = acc2[2 * j].x;     r.y = acc2[2 * j].y;
        r.z = acc2[2 * j + 1].x; r.w = acc2[2 * j + 1].y;
        *(float4*)(op + j * 4) = r;
    }
}

// ---------------- pass 2: combine partials + LayerNorm ---------------------
// 230400 (pos,m) rows of 16; fully coalesced. In-place on part0 (= out).
__global__ __launch_bounds__(256) void caps_ln(
    const float* __restrict__ part1,
    const float* __restrict__ gamma,
    const float* __restrict__ beta,
    float* __restrict__ out)
{
    const size_t t = (size_t)blockIdx.x * 256 + threadIdx.x;  // 0..230399
    const float* p0 = out   + t * 16;
    const float* p1 = part1 + t * 16;

    float a[16];
#pragma unroll
    for (int j = 0; j < 16; j += 4) {
        float4 x = *(const float4*)(p0 + j);
        float4 y = *(const float4*)(p1 + j);
        a[j] = x.x + y.x; a[j+1] = x.y + y.y; a[j+2] = x.z + y.z; a[j+3] = x.w + y.w;
    }

    float mu = 0.0f;
#pragma unroll
    for (int j = 0; j < 16; ++j) mu += a[j];
    mu *= 0.0625f;
    float var = 0.0f;
#pragma unroll
    for (int j = 0; j < 16; ++j) { float d = a[j] - mu; var = fmaf(d, d, var); }
    var *= 0.0625f;
    float rstd = __builtin_amdgcn_rsqf(var + 1e-5f);

    float* op = out + t * 16;
#pragma unroll
    for (int j = 0; j < 16; j += 4) {
        float4 g  = *(const float4*)(gamma + j);
        float4 be = *(const float4*)(beta + j);
        float4 r;
        r.x = (a[j + 0] - mu) * rstd * g.x + be.x;
        r.y = (a[j + 1] - mu) * rstd * g.y + be.y;
        r.z = (a[j + 2] - mu) * rstd * g.z + be.z;
        r.w = (a[j + 3] - mu) * rstd * g.w + be.w;
        *(float4*)(op + j) = r;
    }
}

extern "C" void kernel_launch(void* const* d_in, const int* in_sizes, int n_in,
                              void* d_out, int out_size, void* d_ws, size_t ws_size,
                              hipStream_t stream) {
    const float* input = (const float*)d_in[0];
    const float* ncv   = (const float*)d_in[1];
    const float* wt    = (const float*)d_in[2];
    const float* gamma = (const float*)d_in[3];
    const float* beta  = (const float*)d_in[4];
    float* out = (float*)d_out;
    float* w2  = (float*)d_ws;                    // 576 KB
    float* p1  = (float*)d_ws + 147456;           // 14.06 MiB partial (split 1)

    prep_w<<<dim3(576), dim3(256), 0, stream>>>(wt, w2);
    caps_part<<<dim3(1800, 2), dim3(128), 0, stream>>>(input, ncv, w2, out, p1);
    caps_ln<<<dim3(900), dim3(256), 0, stream>>>(p1, gamma, beta, out);
}

// Round 3
// 392.107 us; speedup vs baseline: 2.9626x; 2.9626x over previous
//
#include <hip/hip_runtime.h>

#define HOUT 15
#define WOUT 15
// input  (32, 32, 32, 32, 16)  fp32
// ncv    (32, 32, 15, 15, 16)  fp32
// w      (3, 3, 32, 4, 4, 32)  fp32
// out    (32, 32, 15, 15, 16)  fp32

typedef float v2 __attribute__((ext_vector_type(2)));

// DPP butterfly add step (ctrl must be a literal)
#define DPP_ADDF(x, ctrl) \
    ((x) + __builtin_bit_cast(float, __builtin_amdgcn_update_dpp( \
        0, __builtin_bit_cast(int, (x)), (ctrl), 0xF, 0xF, true)))

// ---------------- pass 0: transpose w (d <-> m) -----------------------------
// w[kl][n][x][d][m]  ->  w2[n][kl][x][m][d]   (147456 floats = 576 KB)
// so each lane m reads {w[x,0..3,m]} as one float4, coalesced across lanes.
__global__ __launch_bounds__(256) void prep_w(const float* __restrict__ wt,
                                              float* __restrict__ w2)
{
    const int t  = blockIdx.x * 256 + threadIdx.x;   // dest index, 0..147455
    const int d  = t & 3;
    const int m  = (t >> 2) & 31;
    const int x  = (t >> 7) & 3;
    const int r  = t >> 9;        // n*9 + kl
    const int kl = r % 9;
    const int n  = r / 9;
    w2[t] = wt[((((kl * 32 + n) * 4 + x) * 4 + d) * 32) + m];
}

// ---------------- pass 1: attention + accumulate over half the n range -----
// One 32-lane group per output position (b,h,w); lane = m. 4 groups / block.
// blockIdx.y = n-split (0: n=0..15 -> part0=out, 1: n=16..31 -> part1=ws).
// No LDS, no barriers; w read via L1/L2 (18 KB per-n slice, cache-resident).
// Grid 3600 blocks x 2 waves = 28 waves/CU -> 7 waves/SIMD for latency hiding.
// NOTE: no min-waves clause! (128,7) forced a 36-VGPR cap -> scratch spill,
// 2.5 GB HBM traffic/dispatch, 3.4x regression (round 2). Natural alloc is
// ~48 VGPR which already allows 10 waves/SIMD > the 7 the grid supplies.
__global__ __launch_bounds__(128) void caps_part(
    const float* __restrict__ input,
    const float* __restrict__ ncv,
    const float* __restrict__ w2,
    float* __restrict__ part0,
    float* __restrict__ part1)
{
    const int tid  = threadIdx.x;
    const int grp  = tid >> 5;      // 0..3
    const int lane = tid & 31;      // m

    const int pos = blockIdx.x * 4 + grp;      // 0..7199
    const int b   = pos / (HOUT * WOUT);
    const int hw  = pos % (HOUT * WOUT);
    const int h   = hw / WOUT;
    const int wo  = hw % WOUT;
    const int h0  = h * 2, w0 = wo * 2;

    const int n0 = blockIdx.y * 16;

    // ncv[b, m=lane, h, wo, 0..15] as 8 x float2
    const float* ncv_p = ncv + ((((size_t)b * 32 + lane) * HOUT + h) * WOUT + wo) * 16;
    v2 cv2[8];
#pragma unroll
    for (int j = 0; j < 8; ++j) cv2[j] = *(const v2*)(ncv_p + j * 2);

    v2 acc2[8];
#pragma unroll
    for (int j = 0; j < 8; ++j) acc2[j] = (v2){0.0f, 0.0f};

    const float* ip0 = input + ((((size_t)b * 32 + n0) * 32 + h0) * 32 + w0) * 16;
    const float* wp0 = w2 + (size_t)n0 * 4608 + lane * 4;

    for (int ni = 0; ni < 16; ++ni) {
        const float* ipn = ip0 + (size_t)ni * 16384;       // 32*32*16
        const float* wpn = wp0 + (size_t)ni * 4608;        // 9*4*128

#pragma unroll
        for (int kl = 0; kl < 9; ++kl) {
            const int k = kl / 3, l = kl % 3;
            const float* ip = ipn + (k * 32 + l) * 16;

            float av[16];
#pragma unroll
            for (int j = 0; j < 16; j += 4) {
                float4 t4 = *(const float4*)(ip + j);
                av[j] = t4.x; av[j + 1] = t4.y; av[j + 2] = t4.z; av[j + 3] = t4.w;
            }

            // w[x][0..3][m] for this (n,kl): 4 coalesced float4 loads
            const float* wp = wpn + kl * 512;
            float4 wx[4];
#pragma unroll
            for (int x = 0; x < 4; ++x) wx[x] = *(const float4*)(wp + x * 128);

            // u[a,d] = sum_x av[a,x] * w[x,d,m]; packed d-pairs
            v2 u2[8];
#pragma unroll
            for (int x = 0; x < 4; ++x) {
                v2 wlo = {wx[x].x, wx[x].y};
                v2 whi = {wx[x].z, wx[x].w};
#pragma unroll
                for (int a = 0; a < 4; ++a) {
                    v2 sp = {av[a * 4 + x], av[a * 4 + x]};
                    if (x == 0) {
                        u2[a * 2]     = sp * wlo;       // pk_mul: no zero-init
                        u2[a * 2 + 1] = sp * whi;
                    } else {
                        u2[a * 2]     = __builtin_elementwise_fma(sp, wlo, u2[a * 2]);
                        u2[a * 2 + 1] = __builtin_elementwise_fma(sp, whi, u2[a * 2 + 1]);
                    }
                }
            }

            // logit = 0.25 * <u, cv>;  e = exp(logit) = exp2(dot * 0.25*log2e)
            v2 d0 = {0.f, 0.f}, d1 = {0.f, 0.f};
#pragma unroll
            for (int j = 0; j < 4; ++j) {
                d0 = __builtin_elementwise_fma(u2[j],     cv2[j],     d0);
                d1 = __builtin_elementwise_fma(u2[j + 4], cv2[j + 4], d1);
            }
            v2 dd = d0 + d1;
            float e = __builtin_exp2f((dd.x + dd.y) * 0.36067376022224085f);

            // sum over 32 lanes (m): 4 DPP adds + 1 swizzle (xor16)
            // post-xor2 quads are uniform, so half_mirror==xor4, mirror==xor8
            float s = e;
            s = DPP_ADDF(s, 0xB1);    // quad_perm [1,0,3,2]  == xor1
            s = DPP_ADDF(s, 0x4E);    // quad_perm [2,3,0,1]  == xor2
            s = DPP_ADDF(s, 0x141);   // row_half_mirror      == xor4 here
            s = DPP_ADDF(s, 0x140);   // row_mirror           == xor8 here
            s += __builtin_bit_cast(float,
                  __builtin_amdgcn_ds_swizzle(__builtin_bit_cast(int, s), 0x401F)); // xor16

            float p = e * __builtin_amdgcn_rcpf(s);
            v2 p2 = {p, p};
#pragma unroll
            for (int j = 0; j < 8; ++j)
                acc2[j] = __builtin_elementwise_fma(p2, u2[j], acc2[j]);
        }
    }

    // store partial in out-layout: [b][m][h][w][16]
    float* op = (blockIdx.y == 0 ? part0 : part1)
              + ((((size_t)b * 32 + lane) * HOUT + h) * WOUT + wo) * 16;
#pragma unroll
    for (int j = 0; j < 4; ++j) {
        float4 r;
        r.x = acc2[2 * j].x;     r.y = acc2[2 * j].y;
        r.z = acc2[2 * j + 1].x; r.w = acc2[2 * j + 1].y;
        *(float4*)(op + j * 4) = r;
    }
}

// ---------------- pass 2: combine partials + LayerNorm ---------------------
// 230400 (pos,m) rows of 16; fully coalesced. In-place on part0 (= out).
__global__ __launch_bounds__(256) void caps_ln(
    const float* __restrict__ part1,
    const float* __restrict__ gamma,
    const float* __restrict__ beta,
    float* __restrict__ out)
{
    const size_t t = (size_t)blockIdx.x * 256 + threadIdx.x;  // 0..230399
    const float* p0 = out   + t * 16;
    const float* p1 = part1 + t * 16;

    float a[16];
#pragma unroll
    for (int j = 0; j < 16; j += 4) {
        float4 x = *(const float4*)(p0 + j);
        float4 y = *(const float4*)(p1 + j);
        a[j] = x.x + y.x; a[j+1] = x.y + y.y; a[j+2] = x.z + y.z; a[j+3] = x.w + y.w;
    }

    float mu = 0.0f;
#pragma unroll
    for (int j = 0; j < 16; ++j) mu += a[j];
    mu *= 0.0625f;
    float var = 0.0f;
#pragma unroll
    for (int j = 0; j < 16; ++j) { float d = a[j] - mu; var = fmaf(d, d, var); }
    var *= 0.0625f;
    float rstd = __builtin_amdgcn_rsqf(var + 1e-5f);

    float* op = out + t * 16;
#pragma unroll
    for (int j = 0; j < 16; j += 4) {
        float4 g  = *(const float4*)(gamma + j);
        float4 be = *(const float4*)(beta + j);
        float4 r;
        r.x = (a[j + 0] - mu) * rstd * g.x + be.x;
        r.y = (a[j + 1] - mu) * rstd * g.y + be.y;
        r.z = (a[j + 2] - mu) * rstd * g.z + be.z;
        r.w = (a[j + 3] - mu) * rstd * g.w + be.w;
        *(float4*)(op + j) = r;
    }
}

extern "C" void kernel_launch(void* const* d_in, const int* in_sizes, int n_in,
                              void* d_out, int out_size, void* d_ws, size_t ws_size,
                              hipStream_t stream) {
    const float* input = (const float*)d_in[0];
    const float* ncv   = (const float*)d_in[1];
    const float* wt    = (const float*)d_in[2];
    const float* gamma = (const float*)d_in[3];
    const float* beta  = (const float*)d_in[4];
    float* out = (float*)d_out;
    float* w2  = (float*)d_ws;                    // 576 KB
    float* p1  = (float*)d_ws + 147456;           // 14.06 MiB partial (split 1)

    prep_w<<<dim3(576), dim3(256), 0, stream>>>(wt, w2);
    caps_part<<<dim3(1800, 2), dim3(128), 0, stream>>>(input, ncv, w2, out, p1);
    caps_ln<<<dim3(900), dim3(256), 0, stream>>>(p1, gamma, beta, out);
}

// Round 4
// 356.724 us; speedup vs baseline: 3.2564x; 1.0992x over previous
//
#include <hip/hip_runtime.h>

#define HOUT 15
#define WOUT 15
// input  (32, 32, 32, 32, 16)  fp32
// ncv    (32, 32, 15, 15, 16)  fp32
// w      (3, 3, 32, 4, 4, 32)  fp32
// out    (32, 32, 15, 15, 16)  fp32

typedef float v2 __attribute__((ext_vector_type(2)));

// DPP butterfly add step (ctrl must be a literal)
#define DPP_ADDF(x, ctrl) \
    ((x) + __builtin_bit_cast(float, __builtin_amdgcn_update_dpp( \
        0, __builtin_bit_cast(int, (x)), (ctrl), 0xF, 0xF, true)))

// ---------------- pass 0: repack w for the (m, d-half) lane mapping --------
// w[kl][n][x][d][m] -> w3[n][kl][xq][l64][e]  (147456 floats = 576 KB)
// lane l64 = m + 32*half owns d in {2*half, 2*half+1}. Element e of quad xq:
//   x = 2*xq + (e>>1), d = 2*half + (e&1)
// so each lane reads its 8 weights as TWO contiguous float4s (perfectly
// coalesced: 64 lanes x 16 B = 1 KB per load instruction).
__global__ __launch_bounds__(256) void prep_w(const float* __restrict__ wt,
                                              float* __restrict__ w3)
{
    const int t   = blockIdx.x * 256 + threadIdx.x;   // 0..147455
    const int e   = t & 3;
    const int l64 = (t >> 2) & 63;
    const int xq  = (t >> 8) & 1;
    const int r   = t >> 9;          // n*9 + kl
    const int kl  = r % 9;
    const int n   = r / 9;
    const int mm  = l64 & 31;
    const int hf  = l64 >> 5;
    const int x   = 2 * xq + (e >> 1);
    const int d   = 2 * hf + (e & 1);
    w3[t] = wt[((kl * 32 + n) * 16 + x * 4 + d) * 32 + mm];
}

// ---------------- fused kernel: one wave per output position ---------------
// lane = m + 32*half; half owns d-pair {2h, 2h+1}. av (input patch, 16 f)
// is wave-uniform -> readfirstlane'd base -> scalar loads, operands in SGPRs.
// Per site: 2 VMEM (w quads) + 1 SMEM (av) + ~36 VALU. No LDS, no barriers,
// fully fused LayerNorm epilogue (cross-half stats via shfl_xor 32).
// NOTE: no min-waves clause (round 2: forced cap -> spill -> 3.4x regression).
__global__ __launch_bounds__(256) void caps_all(
    const float* __restrict__ input,
    const float* __restrict__ ncv,
    const float* __restrict__ w3,
    const float* __restrict__ gamma,
    const float* __restrict__ beta,
    float* __restrict__ out)
{
    const int tid  = threadIdx.x;
    const int l64  = tid & 63;
    const int m    = l64 & 31;
    const int half = l64 >> 5;

    // wave-uniform position -> force into SGPRs so av loads go scalar
    const int posu = __builtin_amdgcn_readfirstlane(blockIdx.x * 4 + (tid >> 6));
    const int b  = posu / (HOUT * WOUT);
    const int hw = posu % (HOUT * WOUT);
    const int h  = hw / WOUT;
    const int wo = hw % WOUT;

    // input[b][n][h][w][16]: strides 524288 / 16384 / 512 / 16
    const float* ipb = input + (size_t)b * 524288 + (h * 2) * 512 + (wo * 2) * 16;

    // cv[a] = ncv[b][m][h][wo][a*4 + 2*half + {0,1}], pre-scaled by 0.25*log2e
    const float* cvp = ncv + (((size_t)b * 32 + m) * (HOUT * WOUT) + hw) * 16 + 2 * half;
    const float SC = 0.36067376022224085f;   // 0.25 * log2(e)
    v2 sc2 = {SC, SC};
    v2 cv0 = *(const v2*)(cvp +  0) * sc2;
    v2 cv1 = *(const v2*)(cvp +  4) * sc2;
    v2 cv2 = *(const v2*)(cvp +  8) * sc2;
    v2 cv3 = *(const v2*)(cvp + 12) * sc2;

    v2 acc0 = {0.f, 0.f}, acc1 = {0.f, 0.f}, acc2 = {0.f, 0.f}, acc3 = {0.f, 0.f};

    const float* wlane = w3 + l64 * 4;     // + n*4608 + kl*512 (+256 for q1)

    for (int n = 0; n < 32; ++n) {
        const float* ipn = ipb + (size_t)n * 16384;
        const float* wn  = wlane + (size_t)n * 4608;

#pragma unroll
        for (int kl = 0; kl < 9; ++kl) {
            const int k = kl / 3, l = kl % 3;

            // av: 16 floats, wave-uniform address -> s_load (64 B)
            const float* ap = ipn + k * 512 + l * 16;
            const float4 a0 = *(const float4*)(ap + 0);
            const float4 a1 = *(const float4*)(ap + 4);
            const float4 a2 = *(const float4*)(ap + 8);
            const float4 a3 = *(const float4*)(ap + 12);

            // w quads: 2 coalesced dwordx4 per lane
            const float* wp = wn + kl * 512;
            const float4 q0 = *(const float4*)(wp);
            const float4 q1 = *(const float4*)(wp + 256);
            const v2 wx0 = {q0.x, q0.y}, wx1 = {q0.z, q0.w};
            const v2 wx2 = {q1.x, q1.y}, wx3 = {q1.z, q1.w};

            // u[a] (this half's d-pair) = sum_x av[a,x] * w[x, dpair, m]
            v2 u0 = (v2){a0.x, a0.x} * wx0;
            u0 = __builtin_elementwise_fma((v2){a0.y, a0.y}, wx1, u0);
            u0 = __builtin_elementwise_fma((v2){a0.z, a0.z}, wx2, u0);
            u0 = __builtin_elementwise_fma((v2){a0.w, a0.w}, wx3, u0);
            v2 u1 = (v2){a1.x, a1.x} * wx0;
            u1 = __builtin_elementwise_fma((v2){a1.y, a1.y}, wx1, u1);
            u1 = __builtin_elementwise_fma((v2){a1.z, a1.z}, wx2, u1);
            u1 = __builtin_elementwise_fma((v2){a1.w, a1.w}, wx3, u1);
            v2 u2 = (v2){a2.x, a2.x} * wx0;
            u2 = __builtin_elementwise_fma((v2){a2.y, a2.y}, wx1, u2);
            u2 = __builtin_elementwise_fma((v2){a2.z, a2.z}, wx2, u2);
            u2 = __builtin_elementwise_fma((v2){a2.w, a2.w}, wx3, u2);
            v2 u3 = (v2){a3.x, a3.x} * wx0;
            u3 = __builtin_elementwise_fma((v2){a3.y, a3.y}, wx1, u3);
            u3 = __builtin_elementwise_fma((v2){a3.z, a3.z}, wx2, u3);
            u3 = __builtin_elementwise_fma((v2){a3.w, a3.w}, wx3, u3);

            // partial (this half's 8 terms of the 16-term dot), cv pre-scaled
            v2 ds = u0 * cv0;
            ds = __builtin_elementwise_fma(u1, cv1, ds);
            ds = __builtin_elementwise_fma(u2, cv2, ds);
            ds = __builtin_elementwise_fma(u3, cv3, ds);
            float part = ds.x + ds.y;
            float lg   = part + __shfl_xor(part, 32, 64);   // full scaled logit
            float e1   = __builtin_exp2f(lg);

            // softmax denom over m (each 32-half independently; identical)
            float s = e1;
            s = DPP_ADDF(s, 0xB1);    // xor1
            s = DPP_ADDF(s, 0x4E);    // xor2
            s = DPP_ADDF(s, 0x141);   // xor4 (row_half_mirror)
            s = DPP_ADDF(s, 0x140);   // xor8 (row_mirror)
            s += __builtin_bit_cast(float,
                  __builtin_amdgcn_ds_swizzle(__builtin_bit_cast(int, s), 0x401F)); // xor16

            float p = e1 * __builtin_amdgcn_rcpf(s);
            v2 p2 = {p, p};
            acc0 = __builtin_elementwise_fma(p2, u0, acc0);
            acc1 = __builtin_elementwise_fma(p2, u1, acc1);
            acc2 = __builtin_elementwise_fma(p2, u2, acc2);
            acc3 = __builtin_elementwise_fma(p2, u3, acc3);
        }
    }

    // ---- fused LayerNorm: stats over 16 = 8 local + cross-half exchange ----
    v2 s2 = (acc0 + acc1) + (acc2 + acc3);
    float s8  = s2.x + s2.y;
    float s16 = s8 + __shfl_xor(s8, 32, 64);
    float mu  = s16 * 0.0625f;
    v2 mv = {mu, mu};

    v2 vv = {0.f, 0.f};
    v2 t0 = acc0 - mv; vv = __builtin_elementwise_fma(t0, t0, vv);
    v2 t1 = acc1 - mv; vv = __builtin_elementwise_fma(t1, t1, vv);
    v2 t2 = acc2 - mv; vv = __builtin_elementwise_fma(t2, t2, vv);
    v2 t3 = acc3 - mv; vv = __builtin_elementwise_fma(t3, t3, vv);
    float v8  = vv.x + vv.y;
    float v16 = v8 + __shfl_xor(v8, 32, 64);
    float rstd = __builtin_amdgcn_rsqf(v16 * 0.0625f + 1e-5f);
    v2 rs2 = {rstd, rstd};

    const int db = 2 * half;
    float* op = out + (((size_t)b * 32 + m) * (HOUT * WOUT) + hw) * 16 + db;
    {
        v2 g  = *(const v2*)(gamma + 0 + db);
        v2 be = *(const v2*)(beta  + 0 + db);
        *(v2*)(op + 0)  = __builtin_elementwise_fma(t0 * rs2, g, be);
    }
    {
        v2 g  = *(const v2*)(gamma + 4 + db);
        v2 be = *(const v2*)(beta  + 4 + db);
        *(v2*)(op + 4)  = __builtin_elementwise_fma(t1 * rs2, g, be);
    }
    {
        v2 g  = *(const v2*)(gamma + 8 + db);
        v2 be = *(const v2*)(beta  + 8 + db);
        *(v2*)(op + 8)  = __builtin_elementwise_fma(t2 * rs2, g, be);
    }
    {
        v2 g  = *(const v2*)(gamma + 12 + db);
        v2 be = *(const v2*)(beta  + 12 + db);
        *(v2*)(op + 12) = __builtin_elementwise_fma(t3 * rs2, g, be);
    }
}

extern "C" void kernel_launch(void* const* d_in, const int* in_sizes, int n_in,
                              void* d_out, int out_size, void* d_ws, size_t ws_size,
                              hipStream_t stream) {
    const float* input = (const float*)d_in[0];
    const float* ncv   = (const float*)d_in[1];
    const float* wt    = (const float*)d_in[2];
    const float* gamma = (const float*)d_in[3];
    const float* beta  = (const float*)d_in[4];
    float* out = (float*)d_out;
    float* w3  = (float*)d_ws;                 // 576 KB

    prep_w<<<dim3(576), dim3(256), 0, stream>>>(wt, w3);
    caps_all<<<dim3(1800), dim3(256), 0, stream>>>(input, ncv, w3, gamma, beta, out);
}